// Round 2
// baseline (238.138 us; speedup 1.0000x reference)
//
#include <hip/hip_runtime.h>
#include <cstdint>

#define BN_EPS 1e-5f

static constexpr int NB = 8192;
static constexpr int XW = 54;
static constexpr int KWORDS = 128;   // packed h2 words per sample (2 per channel: 32+28)
static constexpr int JLIN = 500;
static constexpr int OWORDS = 16;

// ---------------------------------------------------------------------------
// pack kernel
//  blocks 0..124  : wlin bit-packing (4 j-rows per block, ballot + LDS regroup)
//  blocks 125..132: misc items (lut 512 | m2 576 | wout 160 | bnc2 64)
// ---------------------------------------------------------------------------
__global__ __launch_bounds__(256) void pack_kernel(
    const float* __restrict__ conv1_w, const float* __restrict__ conv1_b,
    const float* __restrict__ conv2_w,
    const float* __restrict__ lin_w, const float* __restrict__ out_w,
    const float* __restrict__ bn1_g, const float* __restrict__ bn1_b,
    const float* __restrict__ bn1_m, const float* __restrict__ bn1_v,
    const float* __restrict__ bn2_g, const float* __restrict__ bn2_b,
    const float* __restrict__ bn2_m, const float* __restrict__ bn2_v,
    uint32_t* __restrict__ wlin, uint32_t* __restrict__ m2,
    uint32_t* __restrict__ lut, uint32_t* __restrict__ wout,
    float* __restrict__ inv2, float* __restrict__ sh2)
{
    int tid = threadIdx.x;
    int b   = blockIdx.x;

    if (b < 125) {
        // ---- wlin packing: rows j = 4b .. 4b+3 ----
        __shared__ uint32_t s_bm[4][122];   // row stride 488 B (8B aligned)
        int lane = tid & 63;
        int wv   = tid >> 6;
        for (int it = 0; it < 60; ++it) {
            int i = it * 256 + tid;                       // 0..15359
            float v = lin_w[(size_t)b * 15360 + i];
            uint64_t mask = __ballot(v > 0.0f);
            if (lane == 0) {
                int bi  = it * 256 + wv * 64;
                int row = bi / 3840;
                int f0  = bi % 3840;
                *((uint64_t*)&s_bm[row][f0 >> 5]) = mask;
            }
        }
        __syncthreads();
        for (int w = tid; w < 512; w += 256) {
            int row = w >> 7, k = w & 127;
            int c = k >> 1, hi = k & 1;
            int nb = hi ? 28 : 32;
            int f0 = c * 60 + hi * 32;
            uint32_t lo  = s_bm[row][f0 >> 5];
            uint32_t hiw = s_bm[row][(f0 >> 5) + 1];
            int sh = f0 & 31;
            uint32_t word = (uint32_t)((((uint64_t)hiw << 32) | lo) >> sh);
            if (nb < 32) word &= (1u << nb) - 1u;
            wlin[(size_t)(b * 4 + row) * KWORDS + k] = word;
        }
        return;
    }

    // ---- misc items ----
    int idx = (b - 125) * 256 + tid;     // 0..2047
    if (idx < 512) {
        // conv1 LUT: word of 32 channel-bits per 9-bit sign pattern
        uint32_t px = (uint32_t)idx;
        uint32_t word = 0;
        for (int c = 0; c < 32; ++c) {
            uint32_t wp = 0;
            for (int t = 0; t < 9; ++t)
                wp |= (conv1_w[c * 9 + t] < 0.0f ? 1u : 0u) << t;
            int d = 9 - 2 * __popc(px ^ wp);
            float inv = bn1_g[c] / sqrtf(bn1_v[c] + BN_EPS);
            float sh  = bn1_b[c] - bn1_m[c] * inv;
            float z = __fadd_rn((float)d, conv1_b[c]);
            z = __fadd_rn(__fmul_rn(z, inv), sh);
            word |= (z > 0.0f ? 1u : 0u) << c;
        }
        lut[idx] = word;
    } else if (idx < 512 + 576) {
        int t = idx - 512;
        int c = t / 9, tap = t % 9;
        uint32_t w = 0;
        for (int ic = 0; ic < 32; ++ic)
            w |= (conv2_w[c * 288 + ic * 9 + tap] > 0.0f ? 1u : 0u) << ic;
        m2[t] = w;
    } else if (idx < 512 + 576 + 160) {
        int t = idx - (512 + 576);
        int j = t >> 4, k = t & 15;
        uint32_t w = 0;
        for (int bb = 0; bb < 32; ++bb) {
            int jj = k * 32 + bb;
            if (jj < JLIN) w |= (out_w[j * 500 + jj] > 0.0f ? 1u : 0u) << bb;
        }
        wout[t] = w;
    } else if (idx < 512 + 576 + 160 + 64) {
        int c = idx - (512 + 576 + 160);
        float inv = bn2_g[c] / sqrtf(bn2_v[c] + BN_EPS);
        inv2[c] = inv;
        sh2[c]  = bn2_b[c] - bn2_m[c] * inv;
    }
}

// ---------------------------------------------------------------------------
// conv kernel: 8 samples/block.
//  phase 1: ballot-pack x sign bits into per-row 64-bit bitmaps
//  phase 2: conv1 via LUT  -> s_in packed words (32 ch bits / position)
//  phase 3: conv2, lane = position, 64-channel loop, SGPR masks, ballot pack
// output h2bT transposed: h2bT[k * 8192 + sample]
// ---------------------------------------------------------------------------
__global__ __launch_bounds__(256) void conv_kernel(
    const float* __restrict__ x,
    const uint32_t* __restrict__ m2,
    const uint32_t* __restrict__ lut,
    const float* __restrict__ conv2_b,
    const float* __restrict__ inv2, const float* __restrict__ sh2,
    uint32_t* __restrict__ h2bT)
{
    __shared__ uint64_t s_rows[8][24];
    __shared__ uint32_t s_lut[512];
    __shared__ uint32_t s_in[8][288];    // 286 used

    int tid  = threadIdx.x;
    int lane = tid & 63;
    int wv   = tid >> 6;
    int s0   = blockIdx.x * 8;

    s_lut[tid]       = lut[tid];
    s_lut[tid + 256] = lut[tid + 256];

    // phase 1: sign bitmap, one row (54 floats) per wave-iteration
    for (int it = 0; it < 48; ++it) {
        int rg = wv * 48 + it;            // 0..191
        int s  = rg / 24, r = rg % 24;
        float v = (lane < 54) ? x[(size_t)(s0 + s) * 1296 + r * 54 + lane] : 1.0f;
        uint64_t mask = __ballot(v < 0.0f);
        if (lane == 0) s_rows[s][r] = mask;
    }
    __syncthreads();

    // phase 2: conv1 via LUT
    for (int i = tid; i < 8 * 286; i += 256) {
        int s = i / 286, p = i - s * 286;
        int oy = p / 26, ox = p - oy * 26;
        uint64_t r0 = s_rows[s][2 * oy];
        uint64_t r1 = s_rows[s][2 * oy + 1];
        uint64_t r2 = s_rows[s][2 * oy + 2];
        int sh = 2 * ox;
        uint32_t px = ((uint32_t)(r0 >> sh) & 7u)
                    | (((uint32_t)(r1 >> sh) & 7u) << 3)
                    | (((uint32_t)(r2 >> sh) & 7u) << 6);
        s_in[s][p] = s_lut[px];
    }
    __syncthreads();

    // phase 3: conv2
    int p  = (lane < 60) ? lane : 59;
    int oy = p / 12, ox = p - 12 * oy;
    for (int si = 0; si < 2; ++si) {
        int s = wv + si * 4;
        uint32_t t[9];
        #pragma unroll
        for (int ky = 0; ky < 3; ++ky) {
            const uint32_t* rp = &s_in[s][(2 * oy + ky) * 26 + 2 * ox];
            t[ky * 3 + 0] = rp[0];
            t[ky * 3 + 1] = rp[1];
            t[ky * 3 + 2] = rp[2];
        }
        int B = 0;
        #pragma unroll
        for (int q = 0; q < 9; ++q) B += __popc(t[q]);

        uint32_t w0 = 0, w1 = 0;
        for (int c = 0; c < 64; ++c) {
            int P = 0;
            #pragma unroll
            for (int q = 0; q < 9; ++q) P += __popc(t[q] & m2[c * 9 + q]);
            float z = __fadd_rn((float)(2 * P - B), conv2_b[c]);
            z = __fadd_rn(__fmul_rn(z, inv2[c]), sh2[c]);
            uint64_t mk = __ballot(z > 0.0f);
            if (lane == c) {
                w0 = (uint32_t)mk;
                w1 = (uint32_t)(mk >> 32) & 0x0FFFFFFFu;
            }
        }
        h2bT[(size_t)(2 * lane) * NB + s0 + s]     = w0;
        h2bT[(size_t)(2 * lane + 1) * NB + s0 + s] = w1;
    }
}

// ---------------------------------------------------------------------------
// lin kernel: zero LDS. lane = sample, wave = 32-j split.
// acts held in 128 VGPRs; wlin rows are wave-uniform loads.
// grid: 512 blocks = 128 sample-groups x 4 split-quads; 4 waves/block.
// ---------------------------------------------------------------------------
__global__ __launch_bounds__(256) void lin_kernel(
    const uint32_t* __restrict__ h2bT,
    const uint32_t* __restrict__ wlin,
    const float* __restrict__ lin_b,
    uint32_t* __restrict__ h3bT)
{
    int lane = threadIdx.x & 63;
    int wv   = __builtin_amdgcn_readfirstlane((int)(threadIdx.x >> 6));
    int g    = blockIdx.x >> 2;
    int jq   = blockIdx.x & 3;
    int split = jq * 4 + wv;             // 0..15
    int jbase = split * 32;
    int s = g * 64 + lane;

    uint32_t act[128];
    #pragma unroll
    for (int k = 0; k < 128; ++k) act[k] = h2bT[(size_t)k * NB + s];

    int B = 0;
    #pragma unroll
    for (int k = 0; k < 128; ++k) B += __popc(act[k]);

    uint32_t w = 0;
    for (int jj = 0; jj < 32; ++jj) {
        int j = jbase + jj;
        if (j < JLIN) {
            const uint32_t* mr = wlin + (size_t)j * KWORDS;
            int P = 0;
            #pragma unroll
            for (int k = 0; k < 128; ++k) P += __popc(act[k] & mr[k]);
            float z = __fadd_rn((float)(2 * P - B), lin_b[j]);
            w |= (z > 0.0f ? 1u : 0u) << jj;
        }
    }
    h3bT[(size_t)split * NB + s] = w;
}

// ---------------------------------------------------------------------------
// out kernel: thread -> (o, s); o wave-uniform => wout via scalar loads.
// ---------------------------------------------------------------------------
__global__ __launch_bounds__(256) void out_kernel(
    const uint32_t* __restrict__ h3bT,
    const uint32_t* __restrict__ wout,
    const float* __restrict__ out_b,
    float* __restrict__ out)
{
    int g = blockIdx.x * 256 + threadIdx.x;   // 0..81919
    int o = g >> 13;                          // 0..9
    int s = g & 8191;
    int P = 0, B = 0;
    #pragma unroll
    for (int k = 0; k < OWORDS; ++k) {
        uint32_t a = h3bT[(size_t)k * NB + s];
        P += __popc(a & wout[o * OWORDS + k]);
        B += __popc(a);
    }
    out[(size_t)s * 10 + o] = __fadd_rn((float)(2 * P - B), out_b[o]);
}

// ---------------------------------------------------------------------------
extern "C" void kernel_launch(void* const* d_in, const int* in_sizes, int n_in,
                              void* d_out, int out_size, void* d_ws, size_t ws_size,
                              hipStream_t stream)
{
    const float* x       = (const float*)d_in[0];
    const float* conv1_w = (const float*)d_in[1];
    const float* conv1_b = (const float*)d_in[2];
    const float* bn1_g   = (const float*)d_in[3];
    const float* bn1_b   = (const float*)d_in[4];
    const float* bn1_m   = (const float*)d_in[5];
    const float* bn1_v   = (const float*)d_in[6];
    const float* conv2_w = (const float*)d_in[7];
    const float* conv2_b = (const float*)d_in[8];
    const float* bn2_g   = (const float*)d_in[9];
    const float* bn2_b   = (const float*)d_in[10];
    const float* bn2_m   = (const float*)d_in[11];
    const float* bn2_v   = (const float*)d_in[12];
    const float* lin_w   = (const float*)d_in[13];
    const float* lin_b   = (const float*)d_in[14];
    const float* out_w   = (const float*)d_in[15];
    const float* out_b   = (const float*)d_in[16];

    char* ws = (char*)d_ws;
    uint32_t* h2bT = (uint32_t*)(ws + 0);            // 128*8192*4 = 4,194,304
    uint32_t* h3bT = (uint32_t*)(ws + 4194304);      // 16*8192*4  =   524,288
    uint32_t* wlin = (uint32_t*)(ws + 4718592);      // 512*128*4  =   262,144
    uint32_t* m2   = (uint32_t*)(ws + 4980736);      // 576*4
    uint32_t* lut  = (uint32_t*)(ws + 4983040);      // 512*4
    uint32_t* wout = (uint32_t*)(ws + 4985088);      // 160*4
    float*    inv2 = (float*)   (ws + 4985728);      // 64*4
    float*    sh2  = (float*)   (ws + 4985984);      // 64*4

    pack_kernel<<<133, 256, 0, stream>>>(conv1_w, conv1_b, conv2_w, lin_w, out_w,
                                         bn1_g, bn1_b, bn1_m, bn1_v,
                                         bn2_g, bn2_b, bn2_m, bn2_v,
                                         wlin, m2, lut, wout, inv2, sh2);
    conv_kernel<<<NB / 8, 256, 0, stream>>>(x, m2, lut, conv2_b, inv2, sh2, h2bT);
    lin_kernel<<<512, 256, 0, stream>>>(h2bT, wlin, lin_b, h3bT);
    out_kernel<<<320, 256, 0, stream>>>(h3bT, wout, out_b, (float*)d_out);
}